// Round 3
// baseline (632.617 us; speedup 1.0000x reference)
//
#include <hip/hip_runtime.h>
#include <stdint.h>

typedef __bf16 bf16;
typedef __bf16 bf16x8 __attribute__((ext_vector_type(8)));
typedef float f32x4 __attribute__((ext_vector_type(4)));

enum { EPI_STORE = 0, EPI_BIAS_RELU = 1, EPI_VRED = 2 };

__device__ __forceinline__ void load_lds16(const bf16* g, bf16* l) {
  __builtin_amdgcn_global_load_lds((const __attribute__((address_space(1))) void*)g,
                                   (__attribute__((address_space(3))) void*)l, 16, 0, 0);
}

// C[M,N] = A[M,K] @ B[K,N], B supplied transposed (Bt[N,K]). All bf16, k-contiguous.
// Tile BM=64 x BN=256 x BK=32, 256 threads = 4 waves, wave tile 32x128.
// Single-barrier prefetch double-buffered K-loop: the barrier's vmcnt(0) drain
// waits on loads issued one iteration ago (overlapped with compute), not cold ones.
template<int EPI>
__global__ __launch_bounds__(256, 3)
void gemm_bt(const bf16* __restrict__ Ap, const bf16* __restrict__ Btp,
             const float* __restrict__ bias, bf16* __restrict__ C,
             float* __restrict__ vpart, const bf16* __restrict__ a0p,
             int K, int ldA, int ldBt, int ldC,
             long sA, long sBt, long sC)
{
  constexpr int BM = 64, BN = 256, BK = 32;
  __shared__ __align__(16) bf16 As[2][BM * BK];   // 2 x 4 KB
  __shared__ __align__(16) bf16 Bs[2][BN * BK];   // 2 x 16 KB

  const int tid  = threadIdx.x;
  const int lane = tid & 63;
  const int wid  = tid >> 6;
  const int wm   = wid & 1;    // m half (32 rows)
  const int wn   = wid >> 1;   // n half (128 cols)
  const int l15  = lane & 15;
  const int quad = lane >> 4;

  const int nb = blockIdx.x, mb = blockIdx.y, g = blockIdx.z;

  // per-thread staging source: row = tid>>2, k-chunk = (tid&3)*8
  const bf16* Ag = Ap + (long)g * sA + (long)(mb * BM + (tid >> 2)) * ldA + (tid & 3) * 8;
  const bf16* Bg = Btp + (long)g * sBt + (long)(nb * BN + (tid >> 2)) * ldBt + (tid & 3) * 8;
  const long bstep = (long)64 * ldBt;

  f32x4 acc[2][8] = {};
  const int nsteps = K / BK;

  // prologue: tile 0 -> buffer 0
  load_lds16(Ag, &As[0][tid * 8]);
  #pragma unroll
  for (int p = 0; p < 4; ++p)
    load_lds16(Bg + p * bstep, &Bs[0][p * 2048 + tid * 8]);

  auto do_step = [&](const bf16* curA, const bf16* curB, bf16* nxtA, bf16* nxtB,
                     int nk, bool pf) {
    __syncthreads();                     // drains vmcnt -> current tile ready
    if (pf) {                            // async prefetch of next tile (fire & forget)
      load_lds16(Ag + nk, nxtA + tid * 8);
      #pragma unroll
      for (int p = 0; p < 4; ++p)
        load_lds16(Bg + p * bstep + nk, nxtB + p * 2048 + tid * 8);
    }
    bf16x8 af[2], bfr[8];
    #pragma unroll
    for (int i = 0; i < 2; ++i)
      af[i] = *(const bf16x8*)&curA[(wm * 32 + i * 16 + l15) * BK + quad * 8];
    #pragma unroll
    for (int j = 0; j < 8; ++j)
      bfr[j] = *(const bf16x8*)&curB[(wn * 128 + j * 16 + l15) * BK + quad * 8];
    #pragma unroll
    for (int i = 0; i < 2; ++i)
      #pragma unroll
      for (int j = 0; j < 8; ++j)
        acc[i][j] = __builtin_amdgcn_mfma_f32_16x16x32_bf16(af[i], bfr[j], acc[i][j], 0, 0, 0);
  };

  for (int s = 0; s < nsteps; s += 2) {   // nsteps is even (4, 8, 32)
    do_step(As[0], Bs[0], As[1], Bs[1], (s + 1) * BK, s + 1 < nsteps);
    do_step(As[1], Bs[1], As[0], Bs[0], (s + 2) * BK, s + 2 < nsteps);
  }

  if constexpr (EPI == EPI_STORE || EPI == EPI_BIAS_RELU) {
    bf16* Cg = C + (long)g * sC;
    #pragma unroll
    for (int i = 0; i < 2; ++i) {
      const int row0 = mb * BM + wm * 32 + i * 16 + quad * 4;
      #pragma unroll
      for (int j = 0; j < 8; ++j) {
        const int col = nb * BN + wn * 128 + j * 16 + l15;
        float bv = 0.f;
        if constexpr (EPI == EPI_BIAS_RELU) bv = bias[col];
        #pragma unroll
        for (int rr = 0; rr < 4; ++rr) {
          float v = acc[i][j][rr];
          if constexpr (EPI == EPI_BIAS_RELU) v = fmaxf(v + bv, 0.f);
          Cg[(long)(row0 + rr) * ldC + col] = (bf16)v;
        }
      }
    }
  } else {  // EPI_VRED: v[col] = sum_rows adj0[row]*relu(C[row][col]+b[col])
    const bf16* a0g = a0p + (long)g * sA + mb * BM;   // adj[g][0][mb*64 ..]
    float a0v[2][4];
    #pragma unroll
    for (int i = 0; i < 2; ++i)
      #pragma unroll
      for (int rr = 0; rr < 4; ++rr)
        a0v[i][rr] = (float)a0g[wm * 32 + i * 16 + quad * 4 + rr];
    __syncthreads();                       // tile buffers free -> reuse as scratch
    float* vsum = (float*)&As[0][0];       // 256 floats (1 KB of 4 KB)
    vsum[tid] = 0.f;
    __syncthreads();
    #pragma unroll
    for (int j = 0; j < 8; ++j) {
      const int col = wn * 128 + j * 16 + l15;
      const float bv = bias[col];
      float p = 0.f;
      #pragma unroll
      for (int i = 0; i < 2; ++i)
        #pragma unroll
        for (int rr = 0; rr < 4; ++rr)
          p += fmaxf(acc[i][j][rr] + bv, 0.f) * a0v[i][rr];
      atomicAdd(&vsum[col], p);
    }
    __syncthreads();
    vpart[((long)g * 16 + mb) * 256 + tid] = vsum[tid];
  }
}

// Convert adj (67.1M f32) and embs (8.4M f32) to bf16. One 8-elem chunk/thread.
__global__ void cvt_prep(const float* __restrict__ adj, const float* __restrict__ embs,
                         bf16* __restrict__ adjb, bf16* __restrict__ embsb)
{
  const long c = (long)blockIdx.x * 256 + threadIdx.x;   // 0 .. 9437183
  const float* src; bf16* dst; long off;
  if (c < 8388608) { src = adj;  dst = adjb;  off = c * 8; }
  else             { src = embs; dst = embsb; off = (c - 8388608) * 8; }
  float4 v0 = *(const float4*)(src + off);
  float4 v1 = *(const float4*)(src + off + 4);
  bf16x8 w;
  w[0]=(bf16)v0.x; w[1]=(bf16)v0.y; w[2]=(bf16)v0.z; w[3]=(bf16)v0.w;
  w[4]=(bf16)v1.x; w[5]=(bf16)v1.y; w[6]=(bf16)v1.z; w[7]=(bf16)v1.w;
  *(bf16x8*)(dst + off) = w;
}

// Transpose + convert weights: W0t[h][k]=W0[k][h] (256x128), W1t[h][k]=W1[k][h] (256x256)
__global__ void prep_w(const float* __restrict__ W0, const float* __restrict__ W1,
                       bf16* __restrict__ W0t, bf16* __restrict__ W1t)
{
  const int idx = blockIdx.x * 256 + threadIdx.x;  // 0..65535
  if (idx < 256 * 128) {
    const int h = idx >> 7, k = idx & 127;
    W0t[idx] = (bf16)W0[k * 256 + h];
  }
  const int h = idx >> 8, k = idx & 255;
  W1t[idx] = (bf16)W1[k * 256 + h];
}

// Per graph: v = sum of 16 partials; h3 = relu(v@W2 + b2); out = h3@Wl + bl (fp32)
__global__ void finish_k(const float* __restrict__ vpart, const float* __restrict__ W2,
                         const float* __restrict__ b2, const float* __restrict__ Wl,
                         const float* __restrict__ bl, float* __restrict__ out)
{
  const int b = blockIdx.x, t = threadIdx.x;
  __shared__ float v[256], h3[256];
  float s = 0.f;
  #pragma unroll
  for (int mb = 0; mb < 16; ++mb) s += vpart[((long)b * 16 + mb) * 256 + t];
  v[t] = s;
  __syncthreads();
  float z = b2[t];
  for (int k = 0; k < 256; ++k) z += v[k] * W2[k * 256 + t];
  h3[t] = fmaxf(z, 0.f);
  __syncthreads();
  if (t < 128) {
    float o = bl[t];
    for (int h = 0; h < 256; ++h) o += h3[h] * Wl[h * 128 + t];
    out[(long)b * 128 + t] = o;
  }
}

extern "C" void kernel_launch(void* const* d_in, const int* in_sizes, int n_in,
                              void* d_out, int out_size, void* d_ws, size_t ws_size,
                              hipStream_t stream) {
  const float* embs = (const float*)d_in[0];  // [64,1024,128]
  const float* adj  = (const float*)d_in[1];  // [64,1024,1024]
  const float* W0   = (const float*)d_in[2];  // [128,256]
  const float* b0   = (const float*)d_in[3];
  const float* W1   = (const float*)d_in[4];  // [256,256]
  const float* b1   = (const float*)d_in[5];
  const float* W2   = (const float*)d_in[6];  // [256,256]
  const float* b2   = (const float*)d_in[7];
  const float* Wl   = (const float*)d_in[8];  // [256,128]
  const float* bl   = (const float*)d_in[9];
  float* out = (float*)d_out;

  char* ws = (char*)d_ws;
  bf16*  adjb  = (bf16*)(ws);                   // 134217728 B
  bf16*  embsb = (bf16*)(ws + 134217728);       // 16777216 B
  bf16*  Zt    = (bf16*)(ws + 150994944);       // [64][256][1024] (Z0t then Z1t)
  bf16*  Hb    = (bf16*)(ws + 184549376);       // [64][1024][256]
  bf16*  W0t   = (bf16*)(ws + 218103808);       // [256][128]
  bf16*  W1t   = (bf16*)(ws + 218169344);       // [256][256]
  float* vpart = (float*)(ws + 218300416);      // [64][16][256] f32

  cvt_prep<<<36864, 256, 0, stream>>>(adj, embs, adjb, embsb);
  prep_w<<<256, 256, 0, stream>>>(W0, W1, W0t, W1t);

  // Z0t[h,n] = sum_k W0t[h,k]*embsb[n,k] : M=256,N=1024,K=128
  gemm_bt<EPI_STORE><<<dim3(4, 4, 64), 256, 0, stream>>>(
      W0t, embsb, nullptr, Zt, nullptr, nullptr,
      128, 128, 128, 1024, 0L, 131072L, 262144L);

  // H1[n,h] = relu(sum_m adjb[n,m]*Z0t[h,m] + b0[h]) : M=1024,N=256,K=1024
  gemm_bt<EPI_BIAS_RELU><<<dim3(1, 16, 64), 256, 0, stream>>>(
      adjb, Zt, b0, Hb, nullptr, nullptr,
      1024, 1024, 1024, 256, 1048576L, 262144L, 262144L);

  // Z1t[h,n] = sum_k W1t[h,k]*H1[n,k] : M=256,N=1024,K=256
  gemm_bt<EPI_STORE><<<dim3(4, 4, 64), 256, 0, stream>>>(
      W1t, Hb, nullptr, Zt, nullptr, nullptr,
      256, 256, 256, 1024, 0L, 262144L, 262144L);

  // vpart[g,mb,h] = sum_{rows in mb} adj0[row]*relu((adjb@Z1t)[row,h] + b1[h])
  gemm_bt<EPI_VRED><<<dim3(1, 16, 64), 256, 0, stream>>>(
      adjb, Zt, b1, nullptr, vpart, adjb,
      1024, 1024, 1024, 256, 1048576L, 262144L, 0L);

  finish_k<<<64, 256, 0, stream>>>(vpart, W2, b2, Wl, bl, out);
}

// Round 4
// 627.320 us; speedup vs baseline: 1.0084x; 1.0084x over previous
//
#include <hip/hip_runtime.h>
#include <stdint.h>

typedef __bf16 bf16;
typedef __bf16 bf16x8 __attribute__((ext_vector_type(8)));
typedef float f32x4 __attribute__((ext_vector_type(4)));

enum { EPI_STORE = 0, EPI_BIAS_RELU = 1, EPI_VRED = 2 };

__device__ __forceinline__ void load_lds16(const bf16* g, bf16* l) {
  __builtin_amdgcn_global_load_lds((const __attribute__((address_space(1))) void*)g,
                                   (__attribute__((address_space(3))) void*)l, 16, 0, 0);
}

// C[M,N] = A[M,K] @ Bt[N,K]^T, all bf16 k-contiguous.
// Block 256 thr = 4 waves; block tile 128x128; wave tile 64x64.
// Each wave has PRIVATE 2-stage LDS ring => ZERO barriers in the K-loop.
// Pipelining via explicit s_waitcnt vmcnt(8): wait only the oldest stage's
// 8 global_load_lds (in-order completion counting), never a full drain.
template<int EPI>
__global__ __launch_bounds__(256, 2)
void gemm_bt(const bf16* __restrict__ Ap, const bf16* __restrict__ Btp,
             const float* __restrict__ bias, bf16* __restrict__ C,
             float* __restrict__ vpart, const bf16* __restrict__ a0p,
             int K, int ldA, int ldBt, int ldC,
             long sA, long sBt, long sC)
{
  __shared__ __align__(16) bf16 As[4][2][64 * 32];  // [wave][stage][row][k], 32 KB
  __shared__ __align__(16) bf16 Bs[4][2][64 * 32];  // [wave][stage][col][k], 32 KB

  const int tid  = threadIdx.x;
  const int lane = tid & 63;
  const int wid  = tid >> 6;
  const int wm   = wid >> 1;   // 64-row strip within 128-row block tile
  const int wn   = wid & 1;    // 64-col strip within 128-col block tile
  const int l15  = lane & 15;
  const int quad = lane >> 4;

  const int nb = blockIdx.x, mb = blockIdx.y, g = blockIdx.z;

  const int lr = lane >> 2;        // staging row within 16-row chunk
  const int lk = (lane & 3) * 8;   // staging k-chunk

  const bf16* Ag = Ap  + (long)g * sA  + (long)(mb * 128 + wm * 64 + lr) * ldA  + lk;
  const bf16* Bg = Btp + (long)g * sBt + (long)(nb * 128 + wn * 64 + lr) * ldBt + lk;

  auto stage = [&](int st, int kt) {   // issue 8 async loads (4 KB A + 4 KB B)
    const int k0 = kt * 32;
    #pragma unroll
    for (int t = 0; t < 4; ++t)
      load_lds16(Ag + (long)t * 16 * ldA + k0, &As[wid][st][t * 512 + lane * 8]);
    #pragma unroll
    for (int t = 0; t < 4; ++t)
      load_lds16(Bg + (long)t * 16 * ldBt + k0, &Bs[wid][st][t * 512 + lane * 8]);
  };

  f32x4 acc[4][4] = {};
  const int nsteps = K / 32;

  stage(0, 0);
  stage(1, 1 % nsteps);

  for (int s = 0; s < nsteps; ++s) {
    // wait until only the newest 8 loads (next stage) are outstanding:
    // current stage is then fully in LDS. No barrier, no full drain.
    asm volatile("s_waitcnt vmcnt(8)" ::: "memory");
    const int st = s & 1;
    bf16x8 af[4], bfr[4];
    #pragma unroll
    for (int i = 0; i < 4; ++i)
      af[i] = *(const bf16x8*)&As[wid][st][(i * 16 + l15) * 32 + quad * 8];
    #pragma unroll
    for (int j = 0; j < 4; ++j)
      bfr[j] = *(const bf16x8*)&Bs[wid][st][(j * 16 + l15) * 32 + quad * 8];
    // frags captured in VGPRs -> safe to overwrite this buffer
    asm volatile("s_waitcnt lgkmcnt(0)" ::: "memory");
    stage(st, (s + 2) % nsteps);   // wrapped tail prefetch keeps vmcnt uniform
    #pragma unroll
    for (int i = 0; i < 4; ++i)
      #pragma unroll
      for (int j = 0; j < 4; ++j)
        acc[i][j] = __builtin_amdgcn_mfma_f32_16x16x32_bf16(af[i], bfr[j], acc[i][j], 0, 0, 0);
  }
  asm volatile("s_waitcnt vmcnt(0)" ::: "memory");   // drain wrapped prefetches

  if constexpr (EPI == EPI_STORE || EPI == EPI_BIAS_RELU) {
    bf16* Cg = C + (long)g * sC;
    #pragma unroll
    for (int i = 0; i < 4; ++i) {
      const int row0 = mb * 128 + wm * 64 + i * 16 + quad * 4;
      #pragma unroll
      for (int j = 0; j < 4; ++j) {
        const int col = nb * 128 + wn * 64 + j * 16 + l15;
        float bv = 0.f;
        if constexpr (EPI == EPI_BIAS_RELU) bv = bias[col];
        #pragma unroll
        for (int rr = 0; rr < 4; ++rr) {
          float v = acc[i][j][rr];
          if constexpr (EPI == EPI_BIAS_RELU) v = fmaxf(v + bv, 0.f);
          Cg[(long)(row0 + rr) * ldC + col] = (bf16)v;
        }
      }
    }
  } else {  // EPI_VRED: v[col] = sum_rows adj0[row]*relu(C[row][col]+b[col])
    const bf16* a0g = a0p + (long)g * sA + mb * 128 + wm * 64;
    float a0v[4][4];
    #pragma unroll
    for (int i = 0; i < 4; ++i)
      #pragma unroll
      for (int rr = 0; rr < 4; ++rr)
        a0v[i][rr] = (float)a0g[i * 16 + quad * 4 + rr];
    __syncthreads();                       // all waves done; LDS reusable
    float* vsum = (float*)&As[0][0][0];    // 128 floats scratch
    if (tid < 128) vsum[tid] = 0.f;
    __syncthreads();
    #pragma unroll
    for (int j = 0; j < 4; ++j) {
      const int lcol = wn * 64 + j * 16 + l15;
      const float bv = bias[nb * 128 + lcol];
      float p = 0.f;
      #pragma unroll
      for (int i = 0; i < 4; ++i)
        #pragma unroll
        for (int rr = 0; rr < 4; ++rr)
          p += fmaxf(acc[i][j][rr] + bv, 0.f) * a0v[i][rr];
      atomicAdd(&vsum[lcol], p);
    }
    __syncthreads();
    if (tid < 128)
      vpart[((long)g * 8 + mb) * 256 + nb * 128 + tid] = vsum[tid];
  }
}

// Convert adj (67.1M f32) and embs (8.4M f32) to bf16. 8 elems/thread.
__global__ void cvt_prep(const float* __restrict__ adj, const float* __restrict__ embs,
                         bf16* __restrict__ adjb, bf16* __restrict__ embsb)
{
  const long c = (long)blockIdx.x * 256 + threadIdx.x;
  const float* src; bf16* dst; long off;
  if (c < 8388608) { src = adj;  dst = adjb;  off = c * 8; }
  else             { src = embs; dst = embsb; off = (c - 8388608) * 8; }
  float4 v0 = *(const float4*)(src + off);
  float4 v1 = *(const float4*)(src + off + 4);
  bf16x8 w;
  w[0]=(bf16)v0.x; w[1]=(bf16)v0.y; w[2]=(bf16)v0.z; w[3]=(bf16)v0.w;
  w[4]=(bf16)v1.x; w[5]=(bf16)v1.y; w[6]=(bf16)v1.z; w[7]=(bf16)v1.w;
  *(bf16x8*)(dst + off) = w;
}

// W0t[h][k]=W0[k][h] (256x128), W1t[h][k]=W1[k][h] (256x256)
__global__ void prep_w(const float* __restrict__ W0, const float* __restrict__ W1,
                       bf16* __restrict__ W0t, bf16* __restrict__ W1t)
{
  const int idx = blockIdx.x * 256 + threadIdx.x;
  if (idx < 256 * 128) {
    const int h = idx >> 7, k = idx & 127;
    W0t[idx] = (bf16)W0[k * 256 + h];
  }
  const int h = idx >> 8, k = idx & 255;
  W1t[idx] = (bf16)W1[k * 256 + h];
}

// v = sum of 8 partials; h3 = relu(v@W2+b2); out = h3@Wl+bl (fp32)
__global__ void finish_k(const float* __restrict__ vpart, const float* __restrict__ W2,
                         const float* __restrict__ b2, const float* __restrict__ Wl,
                         const float* __restrict__ bl, float* __restrict__ out)
{
  const int b = blockIdx.x, t = threadIdx.x;
  __shared__ float v[256], h3[256];
  float s = 0.f;
  #pragma unroll
  for (int mb = 0; mb < 8; ++mb) s += vpart[((long)b * 8 + mb) * 256 + t];
  v[t] = s;
  __syncthreads();
  float z = b2[t];
  for (int k = 0; k < 256; ++k) z += v[k] * W2[k * 256 + t];
  h3[t] = fmaxf(z, 0.f);
  __syncthreads();
  if (t < 128) {
    float o = bl[t];
    for (int h = 0; h < 256; ++h) o += h3[h] * Wl[h * 128 + t];
    out[(long)b * 128 + t] = o;
  }
}

extern "C" void kernel_launch(void* const* d_in, const int* in_sizes, int n_in,
                              void* d_out, int out_size, void* d_ws, size_t ws_size,
                              hipStream_t stream) {
  const float* embs = (const float*)d_in[0];
  const float* adj  = (const float*)d_in[1];
  const float* W0   = (const float*)d_in[2];
  const float* b0   = (const float*)d_in[3];
  const float* W1   = (const float*)d_in[4];
  const float* b1   = (const float*)d_in[5];
  const float* W2   = (const float*)d_in[6];
  const float* b2   = (const float*)d_in[7];
  const float* Wl   = (const float*)d_in[8];
  const float* bl   = (const float*)d_in[9];
  float* out = (float*)d_out;

  char* ws = (char*)d_ws;
  bf16*  adjb  = (bf16*)(ws);                   // 134217728 B
  bf16*  embsb = (bf16*)(ws + 134217728);       // 16777216 B
  bf16*  Zt    = (bf16*)(ws + 150994944);       // [64][256][1024]
  bf16*  Hb    = (bf16*)(ws + 184549376);       // [64][1024][256]
  bf16*  W0t   = (bf16*)(ws + 218103808);       // [256][128]
  bf16*  W1t   = (bf16*)(ws + 218169344);       // [256][256]
  float* vpart = (float*)(ws + 218300416);      // [64][8][256] f32

  cvt_prep<<<36864, 256, 0, stream>>>(adj, embs, adjb, embsb);
  prep_w<<<256, 256, 0, stream>>>(W0, W1, W0t, W1t);

  // Z0t[h,n]: M=256,N=1024,K=128
  gemm_bt<EPI_STORE><<<dim3(8, 2, 64), 256, 0, stream>>>(
      W0t, embsb, nullptr, Zt, nullptr, nullptr,
      128, 128, 128, 1024, 0L, 131072L, 262144L);

  // H1[n,h] = relu(adjb@Z0t + b0): M=1024,N=256,K=1024
  gemm_bt<EPI_BIAS_RELU><<<dim3(2, 8, 64), 256, 0, stream>>>(
      adjb, Zt, b0, Hb, nullptr, nullptr,
      1024, 1024, 1024, 256, 1048576L, 262144L, 262144L);

  // Z1t[h,n]: M=256,N=1024,K=256
  gemm_bt<EPI_STORE><<<dim3(8, 2, 64), 256, 0, stream>>>(
      W1t, Hb, nullptr, Zt, nullptr, nullptr,
      256, 256, 256, 1024, 0L, 262144L, 262144L);

  // vpart[g,mb,:]: reduction epilogue over adj@Z1t: M=1024,N=256,K=1024
  gemm_bt<EPI_VRED><<<dim3(2, 8, 64), 256, 0, stream>>>(
      adjb, Zt, b1, nullptr, vpart, adjb,
      1024, 1024, 1024, 256, 1048576L, 262144L, 0L);

  finish_k<<<64, 256, 0, stream>>>(vpart, W2, b2, Wl, bl, out);
}